// Round 11
// baseline (502.296 us; speedup 1.0000x reference)
//
#include <hip/hip_runtime.h>
#include <math.h>

#define B_   128
#define L_   32
#define T_   31
#define V_   10000
#define IC_  2048
#define WD_  512
#define H_   512
#define D_   2560
#define G3_  1536   // 3*H
#define NPAD_ 10112 // V padded to 79*128
#define NPROD_ 64                 // producer blocks (solo CUs)
#define NCONS_ 158                // consumers = 79 nb-slots x 2 teams
#define NTEAM_ 2
// k_setup block-role layout
#define SU_PFX0 1
#define SU_GI0  17                // [17, 389): gi_wemb tiles (31*12)
#define SU_FCW0 389               // [389, 2917)
#define SU_WHH0 2917              // [2917, 3301)
#define SU_N    3301

typedef short short8 __attribute__((ext_vector_type(8)));
typedef float f32x4  __attribute__((ext_vector_type(4)));
typedef unsigned short ushort_t;
typedef unsigned long long ull_t;

__device__ __forceinline__ unsigned short f2bf(float f) {
    unsigned int u = __builtin_bit_cast(unsigned int, f);
    unsigned int r = (u + 0x7FFFu + ((u >> 16) & 1u)) >> 16;
    return (unsigned short)r;
}
__device__ __forceinline__ float bf2f(unsigned short h) {
    unsigned int u = ((unsigned int)h) << 16;
    return __builtin_bit_cast(float, u);
}
__device__ __forceinline__ f32x4 mfma16(short8 a, short8 b, f32x4 c) {
    return __builtin_amdgcn_mfma_f32_16x16x32_bf16(a, b, c, 0, 0, 0);
}

// ---- workspace layout (byte offsets) ----
#define WS_ORDER  0          // int[128]
#define WS_LEN    512        // int[128]
#define WS_BAR    16896      // int (legacy, zeroed)
#define WS_GIIMG  16960      // float[128*1536]          -> ends 803392
#define WS_WHH    803392     // bf16 [32][48][512] perm  -> ends 2376256
#define WS_GIWEMB 2376256    // bf16 [3968*1536]         -> ends 14565952
#define WS_OUTS   14565952   // bf16 [32*128*512]        -> ends 18760256
#define WS_FCW    18760256   // bf16 [10112*512]         -> ends 29114944
// sync flags live inside the zero-padded fcw rows [10108,10112) (4096 B):
//   - zeroed every iteration by the cvt_fcw role (rows >= V_ write 0)
//   - read as B-operand only for output cols n >= V_, which are masked
//   int sync[i*8]          : per-producer flag i in [0,64), value = step+1
//   int sync[768 + k*16+ih]: half-ready replica k in [0,8) (8B-pair loadable)

// ---------------------------------------------------------------------------
template<bool F32>
__device__ __forceinline__ uint4 load_cvt(const void* src, size_t off) {
    if constexpr (!F32) {
        return *(const uint4*)((const unsigned short*)src + off);
    } else {
        const float* p = (const float*)src + off;
        const float4 x = *(const float4*)p;
        const float4 y = *(const float4*)(p + 4);
        union { unsigned short u[8]; uint4 v; } r;
        r.u[0]=f2bf(x.x); r.u[1]=f2bf(x.y); r.u[2]=f2bf(x.z); r.u[3]=f2bf(x.w);
        r.u[4]=f2bf(y.x); r.u[5]=f2bf(y.y); r.u[6]=f2bf(y.z); r.u[7]=f2bf(y.w);
        return r.v;
    }
}

// ---------------------------------------------------------------------------
// k_setup: ONE launch for ALL preprocessing (verbatim R7).
// ---------------------------------------------------------------------------
__global__ __launch_bounds__(256) void k_setup(
    const int* __restrict__ captions,
    const int* __restrict__ cap_lens,
    const float* __restrict__ fc_w,
    const float* __restrict__ W_hh,
    const float* __restrict__ image_code,
    const float* __restrict__ W_ih,
    const float* __restrict__ b_ih,
    const float* __restrict__ init_w,
    const float* __restrict__ init_b,
    const float* __restrict__ embed_w,
    ushort_t* __restrict__ fcw_bf,
    ushort_t* __restrict__ whh_bf,
    float* __restrict__ gi_img,
    ushort_t* __restrict__ gi_wemb,
    ushort_t* __restrict__ outs,
    int* __restrict__ order,
    int* __restrict__ len_i,
    int* __restrict__ bar,
    float* __restrict__ out_tail)
{
    __shared__ __align__(16) ushort_t As[128 * 32];
    __shared__ __align__(16) ushort_t Bs[128 * 32];
    __shared__ int s_len[B_];
    __shared__ int s_ord[B_];
    const int bid = blockIdx.x;
    const int tid = threadIdx.x;

    if (bid >= SU_FCW0 && bid < SU_WHH0) {
        const int idx = (bid - SU_FCW0) * 256 + tid;
        const int row = idx >> 6;
        const int ch  = idx & 63;
        union { unsigned short u[8]; uint4 v; } r;
        if (row < V_) {
            const float* p = fc_w + (size_t)row * 512 + ch * 8;
            const float4 x = *(const float4*)p;
            const float4 y = *(const float4*)(p + 4);
            r.u[0]=f2bf(x.x); r.u[1]=f2bf(x.y); r.u[2]=f2bf(x.z); r.u[3]=f2bf(x.w);
            r.u[4]=f2bf(y.x); r.u[5]=f2bf(y.y); r.u[6]=f2bf(y.z); r.u[7]=f2bf(y.w);
        } else {
            r.v = make_uint4(0, 0, 0, 0);
        }
        *(uint4*)&fcw_bf[(size_t)row * 512 + ch * 8] = r.v;
        return;
    }
    if (bid >= SU_WHH0) {
        const int idx = (bid - SU_WHH0) * 256 + tid;
        const size_t o = (size_t)idx * 8;
        const int g = (int)(o / (48 * 512));
        const int rem = (int)(o % (48 * 512));
        const int j = rem >> 9;
        const int k = rem & 511;
        const int srow = (j >> 4) * 512 + g * 16 + (j & 15);
        const float* p = W_hh + (size_t)srow * 512 + k;
        const float4 x = *(const float4*)p;
        const float4 y = *(const float4*)(p + 4);
        union { unsigned short u[8]; uint4 v; } r;
        r.u[0]=f2bf(x.x); r.u[1]=f2bf(x.y); r.u[2]=f2bf(x.z); r.u[3]=f2bf(x.w);
        r.u[4]=f2bf(y.x); r.u[5]=f2bf(y.y); r.u[6]=f2bf(y.z); r.u[7]=f2bf(y.w);
        *(uint4*)&whh_bf[o] = r.v;
        return;
    }

    if (tid < B_) s_len[tid] = cap_lens[tid];
    __syncthreads();
    if (tid < B_) {
        const int myl = s_len[tid];
        int rank = 0;
        for (int k = 0; k < B_; ++k) {
            const int lk = s_len[k];
            if (lk > myl || (lk == myl && k < tid)) rank++;
        }
        s_ord[rank] = tid;
    }
    __syncthreads();

    if (bid == 0) {
        if (tid == 0) *bar = 0;
        if (tid < B_) {
            const int o = s_ord[tid];
            order[tid] = o;
            const int ln = s_len[o] - 1;
            len_i[tid] = ln;
            out_tail[B_ * L_ + tid]      = (float)ln;
            out_tail[B_ * L_ + B_ + tid] = (float)o;
        }
        __syncthreads();
        for (int i = tid; i < B_ * L_; i += 256) {
            const int b = i / L_, l = i % L_;
            out_tail[i] = (float)captions[s_ord[b] * L_ + l];
        }
        return;
    }

    const int w = tid >> 6, lane = tid & 63, quad = lane >> 4, lr = lane & 15;
    const int srow = tid >> 2, ch = tid & 3;
    const int wm = (w & 1) * 64, wn = (w >> 1) * 64;

    f32x4 acc[4][4];
    const f32x4 z4 = {0.f, 0.f, 0.f, 0.f};
#pragma unroll
    for (int i = 0; i < 4; ++i)
#pragma unroll
        for (int j = 0; j < 4; ++j) acc[i][j] = z4;

    if (bid >= SU_GI0) {
        const int ti = bid - SU_GI0;
        const int t = ti / 12, nt = ti - t * 12;
        const int n0 = nt * 128;
        const int ar0 = captions[s_ord[srow]      * L_ + t];
        const int ar1 = captions[s_ord[srow + 64] * L_ + t];
        const int br0 = n0 + srow, br1 = n0 + srow + 64;
        const float* Wt = W_ih + IC_;

        uint4 a0 = load_cvt<true>(embed_w, (size_t)ar0 * WD_ + ch * 8);
        uint4 a1 = load_cvt<true>(embed_w, (size_t)ar1 * WD_ + ch * 8);
        uint4 b0 = load_cvt<true>(Wt, (size_t)br0 * D_ + ch * 8);
        uint4 b1 = load_cvt<true>(Wt, (size_t)br1 * D_ + ch * 8);

        for (int k0 = 0; k0 < WD_; k0 += 32) {
            __syncthreads();
            *(uint4*)&As[(srow)      * 32 + ch * 8] = a0;
            *(uint4*)&As[(srow + 64) * 32 + ch * 8] = a1;
            *(uint4*)&Bs[(srow)      * 32 + ch * 8] = b0;
            *(uint4*)&Bs[(srow + 64) * 32 + ch * 8] = b1;
            __syncthreads();
            short8 af[4], bfr[4];
#pragma unroll
            for (int i = 0; i < 4; ++i) af[i]  = *(const short8*)&As[(wm + i * 16 + lr) * 32 + quad * 8];
#pragma unroll
            for (int j = 0; j < 4; ++j) bfr[j] = *(const short8*)&Bs[(wn + j * 16 + lr) * 32 + quad * 8];
            if (k0 + 32 < WD_) {
                a0 = load_cvt<true>(embed_w, (size_t)ar0 * WD_ + k0 + 32 + ch * 8);
                a1 = load_cvt<true>(embed_w, (size_t)ar1 * WD_ + k0 + 32 + ch * 8);
                b0 = load_cvt<true>(Wt, (size_t)br0 * D_ + k0 + 32 + ch * 8);
                b1 = load_cvt<true>(Wt, (size_t)br1 * D_ + k0 + 32 + ch * 8);
            }
#pragma unroll
            for (int i = 0; i < 4; ++i)
#pragma unroll
                for (int j = 0; j < 4; ++j) acc[i][j] = mfma16(af[i], bfr[j], acc[i][j]);
        }

#pragma unroll
        for (int i = 0; i < 4; ++i)
#pragma unroll
            for (int r = 0; r < 4; ++r) {
                const int m = t * 128 + wm + i * 16 + quad * 4 + r;
#pragma unroll
                for (int j = 0; j < 4; ++j) {
                    const int n = n0 + wn + j * 16 + lr;
                    gi_wemb[(size_t)m * G3_ + n] = f2bf(acc[i][j][r]);
                }
            }
        return;
    }

    // ---- pfx: gi_img (bids 1..12) / h0 (bids 13..16), K = 2048 ----
    const int px = bid - SU_PFX0;
    const bool isH0 = px >= 12;
    const float* Bm = isH0 ? init_w : W_ih;
    const int ldb = isH0 ? IC_ : D_;
    const int n0 = isH0 ? (px - 12) * 128 : px * 128;
    const float* bias = isH0 ? init_b : b_ih;

    const int ar0 = s_ord[srow];
    const int ar1 = s_ord[srow + 64];
    const int br0 = n0 + srow, br1 = n0 + srow + 64;

    uint4 a0 = load_cvt<true>(image_code, (size_t)ar0 * IC_ + ch * 8);
    uint4 a1 = load_cvt<true>(image_code, (size_t)ar1 * IC_ + ch * 8);
    uint4 b0 = load_cvt<true>(Bm, (size_t)br0 * ldb + ch * 8);
    uint4 b1 = load_cvt<true>(Bm, (size_t)br1 * ldb + ch * 8);

    for (int k0 = 0; k0 < IC_; k0 += 32) {
        __syncthreads();
        *(uint4*)&As[(srow)      * 32 + ch * 8] = a0;
        *(uint4*)&As[(srow + 64) * 32 + ch * 8] = a1;
        *(uint4*)&Bs[(srow)      * 32 + ch * 8] = b0;
        *(uint4*)&Bs[(srow + 64) * 32 + ch * 8] = b1;
        __syncthreads();
        short8 af[4], bfr[4];
#pragma unroll
        for (int i = 0; i < 4; ++i) af[i]  = *(const short8*)&As[(wm + i * 16 + lr) * 32 + quad * 8];
#pragma unroll
        for (int j = 0; j < 4; ++j) bfr[j] = *(const short8*)&Bs[(wn + j * 16 + lr) * 32 + quad * 8];
        if (k0 + 32 < IC_) {
            a0 = load_cvt<true>(image_code, (size_t)ar0 * IC_ + k0 + 32 + ch * 8);
            a1 = load_cvt<true>(image_code, (size_t)ar1 * IC_ + k0 + 32 + ch * 8);
            b0 = load_cvt<true>(Bm, (size_t)br0 * ldb + k0 + 32 + ch * 8);
            b1 = load_cvt<true>(Bm, (size_t)br1 * ldb + k0 + 32 + ch * 8);
        }
#pragma unroll
        for (int i = 0; i < 4; ++i)
#pragma unroll
            for (int j = 0; j < 4; ++j) acc[i][j] = mfma16(af[i], bfr[j], acc[i][j]);
    }

#pragma unroll
    for (int i = 0; i < 4; ++i)
#pragma unroll
        for (int r = 0; r < 4; ++r) {
            const int m = wm + i * 16 + quad * 4 + r;
#pragma unroll
            for (int j = 0; j < 4; ++j) {
                const int n = n0 + wn + j * 16 + lr;
                const float v = acc[i][j][r] + bias[n];
                if (isH0) outs[(size_t)m * H_ + n] = f2bf(v);
                else      gi_img[(size_t)m * G3_ + n] = v;
            }
        }
}

// ---------------------------------------------------------------------------
// FUSED recurrence + output projection — R7 structure verbatim, except the
// consumer k-loop uses a 3-DEEP register prefetch (R11): loads for chunk
// it+3 are issued ~2 full iterations before they are staged, covering the
// ~700-900cy L3 latency that made each of the 16 k-iters latency-bound
// (the consumer side, 2 teams x 16 tiles x ~11us, is the theory for why
// k_fused has been pinned at ~184us since R5). Same kk order -> bit-identical.
// ---------------------------------------------------------------------------
#define PBS_STR 520
__global__ __launch_bounds__(256, 1) void k_fused(
    const ushort_t* __restrict__ whh_bf,   // (32,48,512)
    const ushort_t* __restrict__ gi_wemb,  // (31*128,1536) pure emb part
    const float* __restrict__ b_hh,        // (1536)
    ushort_t* __restrict__ outs,           // (32,128,512)
    const ushort_t* __restrict__ fcw_bf,   // (10112,512)
    const float* __restrict__ fc_b,        // (10000)
    const int* __restrict__ len_i,         // (128)
    float* __restrict__ out,               // (128,31,10000)
    int* __restrict__ sync,                // distributed flags (fcw pad rows)
    const float* __restrict__ gi_img)      // (128,1536) f32
{
    __shared__ __align__(16) ushort_t sm[43008];   // 86,016 B -> 1 block/CU
    const int bid = blockIdx.x;
    const int tid = threadIdx.x;
    const int w = tid >> 6, lane = tid & 63, quad = lane >> 4, lr = lane & 15;

    if (bid < NPROD_) {
        // ---------------- producer (solo CU) ----------------
        __builtin_amdgcn_s_setprio(1);
        const int g = bid & 31;
        const int ih = bid >> 5;
        const bool leader = (bid == (ih << 5));   // bid 0 and 32
        ushort_t* Bs = sm;                 // 48 x 520

        const ushort_t* wsrc = whh_bf + (size_t)g * 48 * 512;
        for (int i = tid; i < 48 * 64; i += 256) {
            const int row = i >> 6, c = i & 63;
            *(uint4*)&Bs[row * PBS_STR + c * 8] = *(const uint4*)&wsrc[row * 512 + c * 8];
        }
        const int cg = g * 16 + lr;        // gh col
        const float bhr = b_hh[cg];
        const float bhz = b_hh[512 + cg];
        const float bhn = b_hh[1024 + cg];
        __syncthreads();

        // constants per thread: gi_img (step-invariant) + h0
        float gim0[4], gim1[4], gim2[4];
        float hold_reg[4];
        {
            const ushort_t* h0p = outs + (size_t)ih * 64 * 512;
#pragma unroll
            for (int r = 0; r < 4; ++r) {
                const int b = ih * 64 + w * 16 + quad * 4 + r;
                const float* pim = gi_img + (size_t)b * G3_ + cg;
                gim0[r] = pim[0]; gim1[r] = pim[512]; gim2[r] = pim[1024];
                hold_reg[r] = bf2f(h0p[(size_t)(w * 16 + quad * 4 + r) * 512 + cg]);
            }
        }
        // gi prefetch for step 0
        ushort_t gi0[4], gi1[4], gi2[4];
#pragma unroll
        for (int r = 0; r < 4; ++r) {
            const int b = ih * 64 + w * 16 + quad * 4 + r;
            const ushort_t* p = gi_wemb + (size_t)b * G3_ + cg;
            gi0[r] = p[0]; gi1[r] = p[512]; gi2[r] = p[1024];
        }

        for (int step = 0; step < T_; ++step) {
            const ushort_t* hsrc = outs + (size_t)step * (128 * 512) + (size_t)ih * 64 * 512;

            // h_t A-fragments: per-lane contiguous 16B chunks straight to regs
            uint4 hv[16];
            const ushort_t* hrow = hsrc + (size_t)(w * 16 + lr) * 512 + quad * 8;
#pragma unroll
            for (int kk = 0; kk < 16; ++kk)
                hv[kk] = *(const uint4*)(hrow + kk * 32);

            f32x4 acc[3];
#pragma unroll
            for (int j = 0; j < 3; ++j) acc[j] = (f32x4){0.f, 0.f, 0.f, 0.f};
#pragma unroll
            for (int kk = 0; kk < 16; ++kk) {
                union { uint4 v; short8 s; } cc; cc.v = hv[kk];
                const short8 af = cc.s;
#pragma unroll
                for (int j = 0; j < 3; ++j) {
                    const short8 bf = *(const short8*)&Bs[(j * 16 + lr) * PBS_STR + kk * 32 + quad * 8];
                    acc[j] = mfma16(af, bf, acc[j]);
                }
            }

            // gates (C-layout: col=lr, row=quad*4+r)
            ushort_t* hdst = outs + (size_t)(step + 1) * (128 * 512);
#pragma unroll
            for (int r = 0; r < 4; ++r) {
                const int b = ih * 64 + w * 16 + quad * 4 + r;
                const float ir  = bf2f(gi0[r]) + gim0[r] + bhr;
                const float iz  = bf2f(gi1[r]) + gim1[r] + bhz;
                const float in_ = bf2f(gi2[r]) + gim2[r];
                const float hr = acc[0][r];
                const float hz = acc[1][r];
                const float hn = acc[2][r] + bhn;
                const float rg = 1.f / (1.f + __expf(-(ir + hr)));
                const float zg = 1.f / (1.f + __expf(-(iz + hz)));
                const float nn = tanhf(in_ + rg * hn);
                const float hnew = (1.f - zg) * nn + zg * hold_reg[r];
                const unsigned int hb = (unsigned int)f2bf(hnew);
                hold_reg[r] = bf2f((unsigned short)hb);   // bit-compat carry
                const unsigned int pv = (unsigned int)__shfl_xor((int)hb, 1);
                if ((lr & 1) == 0) {
                    const unsigned int word = hb | (pv << 16);
                    __hip_atomic_store((unsigned int*)&hdst[(size_t)b * 512 + cg], word,
                                       __ATOMIC_RELAXED, __HIP_MEMORY_SCOPE_AGENT);
                }
            }

            // release: drain write-through stores, then distributed signal
            asm volatile("s_waitcnt vmcnt(0)" ::: "memory");
            __syncthreads();
            const int tgt = step + 1;
            if (tid == 0)
                __hip_atomic_store(&sync[bid * 8], tgt,
                                   __ATOMIC_RELAXED, __HIP_MEMORY_SCOPE_AGENT);

            // prefetch next step's gi (independent of h) under the wait
            ushort_t ng0[4], ng1[4], ng2[4];
            if (step + 1 < T_) {
                const size_t gb = (size_t)(step + 1) * 128 * G3_;
#pragma unroll
                for (int r = 0; r < 4; ++r) {
                    const int b = ih * 64 + w * 16 + quad * 4 + r;
                    const ushort_t* p = gi_wemb + gb + (size_t)b * G3_ + cg;
                    ng0[r] = p[0]; ng1[r] = p[512]; ng2[r] = p[1024];
                }
            }
            asm volatile("" ::: "memory");

            // wave 0 only polls the 32 same-half flags, with backoff
            if (w == 0 && (step < T_ - 1 || leader)) {
                const int* pf = &sync[(ih * 32 + (lane & 31)) * 8];
                for (;;) {
                    const int v = __hip_atomic_load(pf, __ATOMIC_RELAXED, __HIP_MEMORY_SCOPE_AGENT);
                    if (__all(v >= tgt)) break;
                    __builtin_amdgcn_s_sleep(1);
                }
                if (leader && lane == 0) {
#pragma unroll
                    for (int k = 0; k < 8; ++k)
                        __hip_atomic_store(&sync[768 + k * 16 + ih], tgt,
                                           __ATOMIC_RELAXED, __HIP_MEMORY_SCOPE_AGENT);
                }
            }
            __syncthreads();          // release waves 1-3
            asm volatile("" ::: "memory");

            if (step + 1 < T_) {
#pragma unroll
                for (int r = 0; r < 4; ++r) { gi0[r] = ng0[r]; gi1[r] = ng1[r]; gi2[r] = ng2[r]; }
            }
        }
    } else {
        // ------- nb-affine consumer (solo CU) -- R7 + 3-deep prefetch -------
        const int cid = bid - NPROD_;          // [0, 158)
        const int nb = cid % 79;               // FIXED fcw slab per block
        const int team = cid / 79;             // {0, 1}
        const int n0 = nb * 128;
        ushort_t* As = sm;            // 128 x 32
        ushort_t* Bs = sm + 4096;     // 128 x 32
        const int srow = tid >> 2, ch = tid & 3;
        const int wm = (w & 1) * 64, wn = (w >> 1) * 64;
        const ull_t* hready = (const ull_t*)&sync[768 + (cid & 7) * 16];

        float fcb[4];
#pragma unroll
        for (int j = 0; j < 4; ++j) {
            const int n = n0 + wn + j * 16 + lr;
            fcb[j] = (n < V_) ? fc_b[n] : 0.f;
        }

        for (int t = team; t < T_; t += NTEAM_) {
            if (tid == 0) {
                for (;;) {
                    const ull_t hv8 = __hip_atomic_load(hready, __ATOMIC_RELAXED, __HIP_MEMORY_SCOPE_AGENT);
                    const int l0 = (int)(unsigned int)(hv8 & 0xffffffffull);
                    const int l1 = (int)(unsigned int)(hv8 >> 32);
                    if (l0 > t && l1 > t) break;
                    __builtin_amdgcn_s_sleep(16);
                }
            }
            __syncthreads();

            const ushort_t* A = outs + (size_t)(t + 1) * (128 * 512);

            f32x4 acc[4][4];
            const f32x4 z4 = {0.f, 0.f, 0.f, 0.f};
#pragma unroll
            for (int i = 0; i < 4; ++i)
#pragma unroll
                for (int j = 0; j < 4; ++j) acc[i][j] = z4;

            // 3-deep register prefetch: buffers for chunks it, it+1, it+2
            uint4 a0b[3], a1b[3], b0b[3], b1b[3];
#pragma unroll
            for (int p = 0; p < 3; ++p) {
                a0b[p] = *(const uint4*)&A[(size_t)srow * 512 + p * 32 + ch * 8];
                a1b[p] = *(const uint4*)&A[(size_t)(srow + 64) * 512 + p * 32 + ch * 8];
                b0b[p] = *(const uint4*)&fcw_bf[(size_t)(n0 + srow)      * 512 + p * 32 + ch * 8];
                b1b[p] = *(const uint4*)&fcw_bf[(size_t)(n0 + srow + 64) * 512 + p * 32 + ch * 8];
            }

#pragma unroll
            for (int it = 0; it < 16; ++it) {
                const int par = it % 3;        // compile-time (full unroll)
                __syncthreads();
                *(uint4*)&As[(srow)      * 32 + ch * 8] = a0b[par];
                *(uint4*)&As[(srow + 64) * 32 + ch * 8] = a1b[par];
                *(uint4*)&Bs[(srow)      * 32 + ch * 8] = b0b[par];
                *(uint4*)&Bs[(srow + 64) * 32 + ch * 8] = b1b[par];
                __syncthreads();
                short8 af[4], bfr[4];
#pragma unroll
                for (int i = 0; i < 4; ++i) af[i]  = *(const short8*)&As[(wm + i * 16 + lr) * 32 + quad * 8];
#pragma unroll
                for (int j = 0; j < 4; ++j) bfr[j] = *(const short8*)&Bs[(wn + j * 16 + lr) * 32 + quad * 8];
                if (it + 3 < 16) {
                    const int k2 = (it + 3) * 32;
                    a0b[par] = *(const uint4*)&A[(size_t)srow * 512 + k2 + ch * 8];
                    a1b[par] = *(const uint4*)&A[(size_t)(srow + 64) * 512 + k2 + ch * 8];
                    b0b[par] = *(const uint4*)&fcw_bf[(size_t)(n0 + srow)      * 512 + k2 + ch * 8];
                    b1b[par] = *(const uint4*)&fcw_bf[(size_t)(n0 + srow + 64) * 512 + k2 + ch * 8];
                }
#pragma unroll
                for (int i = 0; i < 4; ++i)
#pragma unroll
                    for (int j = 0; j < 4; ++j) acc[i][j] = mfma16(af[i], bfr[j], acc[i][j]);
            }

#pragma unroll
            for (int i = 0; i < 4; ++i)
#pragma unroll
                for (int r = 0; r < 4; ++r) {
                    const int b = wm + i * 16 + quad * 4 + r;
                    const bool act = (t < len_i[b]);
                    const size_t base = (size_t)b * T_ * V_ + (size_t)t * V_;
#pragma unroll
                    for (int j = 0; j < 4; ++j) {
                        const int n = n0 + wn + j * 16 + lr;
                        if (n < V_) out[base + n] = act ? (acc[i][j][r] + fcb[j]) : 0.f;
                    }
                }
        }
    }
}

// ---------------------------------------------------------------------------
extern "C" void kernel_launch(void* const* d_in, const int* in_sizes, int n_in,
                              void* d_out, int out_size, void* d_ws, size_t ws_size,
                              hipStream_t stream) {
    const float* image_code = (const float*)d_in[0];
    const int*   captions   = (const int*)d_in[1];
    const int*   cap_lens   = (const int*)d_in[2];
    const float* embed_w    = (const float*)d_in[3];
    const float* W_ih       = (const float*)d_in[4];
    const float* W_hh       = (const float*)d_in[5];
    const float* b_ih       = (const float*)d_in[6];
    const float* b_hh       = (const float*)d_in[7];
    const float* fc_w       = (const float*)d_in[8];
    const float* fc_b       = (const float*)d_in[9];
    const float* init_w     = (const float*)d_in[10];
    const float* init_b     = (const float*)d_in[11];

    float* out = (float*)d_out;
    char* ws = (char*)d_ws;
    int*      order   = (int*)(ws + WS_ORDER);
    int*      len_i   = (int*)(ws + WS_LEN);
    int*      bar     = (int*)(ws + WS_BAR);
    float*    gi_img  = (float*)(ws + WS_GIIMG);
    ushort_t* whh_bf  = (ushort_t*)(ws + WS_WHH);
    ushort_t* gi_wemb = (ushort_t*)(ws + WS_GIWEMB);
    ushort_t* outs_bf = (ushort_t*)(ws + WS_OUTS);
    ushort_t* fcw_bf  = (ushort_t*)(ws + WS_FCW);
    int*      sync    = (int*)(fcw_bf + ((size_t)NPAD_ - 4) * 512);

    // 1) one setup launch: prep + pfx + gi_wemb gemm + both weight converts
    hipLaunchKernelGGL(k_setup, dim3(SU_N), dim3(256), 0, stream,
                       captions, cap_lens, fc_w, W_hh,
                       image_code, W_ih, b_ih, init_w, init_b, embed_w,
                       fcw_bf, whh_bf, gi_img, gi_wemb, outs_bf,
                       order, len_i, bar,
                       out + (size_t)B_ * T_ * V_);

    // 2) fused persistent recurrence + streaming output projection
    hipLaunchKernelGGL(k_fused, dim3(NPROD_ + NCONS_), dim3(256), 0, stream,
                       whh_bf, gi_wemb, b_hh, outs_bf,
                       fcw_bf, fc_b, len_i, out, sync, gi_img);
}

// Round 12
// 465.080 us; speedup vs baseline: 1.0800x; 1.0800x over previous
//
#include <hip/hip_runtime.h>
#include <math.h>

#define B_   128
#define L_   32
#define T_   31
#define V_   10000
#define IC_  2048
#define WD_  512
#define H_   512
#define D_   2560
#define G3_  1536   // 3*H
#define NPAD_ 10112 // V padded to 79*128
#define NPROD_ 64                 // producer blocks (solo CUs)
#define NCONS_ 158                // consumers = 79 nb-slots x 2 teams
#define NTEAM_ 2
// k_setup block-role layout
#define SU_PFX0 1
#define SU_GI0  17                // [17, 389): gi_wemb tiles (31*12)
#define SU_FCW0 389               // [389, 2917)
#define SU_WHH0 2917              // [2917, 3301)
#define SU_N    3301

typedef short short8 __attribute__((ext_vector_type(8)));
typedef float f32x4  __attribute__((ext_vector_type(4)));
typedef unsigned short ushort_t;
typedef unsigned long long ull_t;

__device__ __forceinline__ unsigned short f2bf(float f) {
    unsigned int u = __builtin_bit_cast(unsigned int, f);
    unsigned int r = (u + 0x7FFFu + ((u >> 16) & 1u)) >> 16;
    return (unsigned short)r;
}
__device__ __forceinline__ float bf2f(unsigned short h) {
    unsigned int u = ((unsigned int)h) << 16;
    return __builtin_bit_cast(float, u);
}
__device__ __forceinline__ f32x4 mfma16(short8 a, short8 b, f32x4 c) {
    return __builtin_amdgcn_mfma_f32_16x16x32_bf16(a, b, c, 0, 0, 0);
}

// ---- workspace layout (byte offsets) ----
#define WS_ORDER  0          // int[128]
#define WS_LEN    512        // int[128]
#define WS_BAR    16896      // int (legacy, zeroed)
#define WS_GIIMG  16960      // float[128*1536]          -> ends 803392
#define WS_WHH    803392     // bf16 [32][48][512] perm  -> ends 2376256
#define WS_GIWEMB 2376256    // bf16 [3968*1536]         -> ends 14565952
#define WS_OUTS   14565952   // bf16 [32*128*512]        -> ends 18760256
#define WS_FCW    18760256   // bf16 [10112*512]         -> ends 29114944
// sync flags live inside the zero-padded fcw rows [10108,10112) (4096 B):
//   int sync[i*8]          : per-producer flag i in [0,64), value = step+1
//   int sync[768 + k*16+ih]: half-ready replica k in [0,8) (8B-pair loadable)

// ---------------------------------------------------------------------------
template<bool F32>
__device__ __forceinline__ uint4 load_cvt(const void* src, size_t off) {
    if constexpr (!F32) {
        return *(const uint4*)((const unsigned short*)src + off);
    } else {
        const float* p = (const float*)src + off;
        const float4 x = *(const float4*)p;
        const float4 y = *(const float4*)(p + 4);
        union { unsigned short u[8]; uint4 v; } r;
        r.u[0]=f2bf(x.x); r.u[1]=f2bf(x.y); r.u[2]=f2bf(x.z); r.u[3]=f2bf(x.w);
        r.u[4]=f2bf(y.x); r.u[5]=f2bf(y.y); r.u[6]=f2bf(y.z); r.u[7]=f2bf(y.w);
        return r.v;
    }
}

// ---------------------------------------------------------------------------
// k_setup: ONE launch for ALL preprocessing (verbatim R7).
// ---------------------------------------------------------------------------
__global__ __launch_bounds__(256) void k_setup(
    const int* __restrict__ captions,
    const int* __restrict__ cap_lens,
    const float* __restrict__ fc_w,
    const float* __restrict__ W_hh,
    const float* __restrict__ image_code,
    const float* __restrict__ W_ih,
    const float* __restrict__ b_ih,
    const float* __restrict__ init_w,
    const float* __restrict__ init_b,
    const float* __restrict__ embed_w,
    ushort_t* __restrict__ fcw_bf,
    ushort_t* __restrict__ whh_bf,
    float* __restrict__ gi_img,
    ushort_t* __restrict__ gi_wemb,
    ushort_t* __restrict__ outs,
    int* __restrict__ order,
    int* __restrict__ len_i,
    int* __restrict__ bar,
    float* __restrict__ out_tail)
{
    __shared__ __align__(16) ushort_t As[128 * 32];
    __shared__ __align__(16) ushort_t Bs[128 * 32];
    __shared__ int s_len[B_];
    __shared__ int s_ord[B_];
    const int bid = blockIdx.x;
    const int tid = threadIdx.x;

    if (bid >= SU_FCW0 && bid < SU_WHH0) {
        const int idx = (bid - SU_FCW0) * 256 + tid;
        const int row = idx >> 6;
        const int ch  = idx & 63;
        union { unsigned short u[8]; uint4 v; } r;
        if (row < V_) {
            const float* p = fc_w + (size_t)row * 512 + ch * 8;
            const float4 x = *(const float4*)p;
            const float4 y = *(const float4*)(p + 4);
            r.u[0]=f2bf(x.x); r.u[1]=f2bf(x.y); r.u[2]=f2bf(x.z); r.u[3]=f2bf(x.w);
            r.u[4]=f2bf(y.x); r.u[5]=f2bf(y.y); r.u[6]=f2bf(y.z); r.u[7]=f2bf(y.w);
        } else {
            r.v = make_uint4(0, 0, 0, 0);
        }
        *(uint4*)&fcw_bf[(size_t)row * 512 + ch * 8] = r.v;
        return;
    }
    if (bid >= SU_WHH0) {
        const int idx = (bid - SU_WHH0) * 256 + tid;
        const size_t o = (size_t)idx * 8;
        const int g = (int)(o / (48 * 512));
        const int rem = (int)(o % (48 * 512));
        const int j = rem >> 9;
        const int k = rem & 511;
        const int srow = (j >> 4) * 512 + g * 16 + (j & 15);
        const float* p = W_hh + (size_t)srow * 512 + k;
        const float4 x = *(const float4*)p;
        const float4 y = *(const float4*)(p + 4);
        union { unsigned short u[8]; uint4 v; } r;
        r.u[0]=f2bf(x.x); r.u[1]=f2bf(x.y); r.u[2]=f2bf(x.z); r.u[3]=f2bf(x.w);
        r.u[4]=f2bf(y.x); r.u[5]=f2bf(y.y); r.u[6]=f2bf(y.z); r.u[7]=f2bf(y.w);
        *(uint4*)&whh_bf[o] = r.v;
        return;
    }

    if (tid < B_) s_len[tid] = cap_lens[tid];
    __syncthreads();
    if (tid < B_) {
        const int myl = s_len[tid];
        int rank = 0;
        for (int k = 0; k < B_; ++k) {
            const int lk = s_len[k];
            if (lk > myl || (lk == myl && k < tid)) rank++;
        }
        s_ord[rank] = tid;
    }
    __syncthreads();

    if (bid == 0) {
        if (tid == 0) *bar = 0;
        if (tid < B_) {
            const int o = s_ord[tid];
            order[tid] = o;
            const int ln = s_len[o] - 1;
            len_i[tid] = ln;
            out_tail[B_ * L_ + tid]      = (float)ln;
            out_tail[B_ * L_ + B_ + tid] = (float)o;
        }
        __syncthreads();
        for (int i = tid; i < B_ * L_; i += 256) {
            const int b = i / L_, l = i % L_;
            out_tail[i] = (float)captions[s_ord[b] * L_ + l];
        }
        return;
    }

    const int w = tid >> 6, lane = tid & 63, quad = lane >> 4, lr = lane & 15;
    const int srow = tid >> 2, ch = tid & 3;
    const int wm = (w & 1) * 64, wn = (w >> 1) * 64;

    f32x4 acc[4][4];
    const f32x4 z4 = {0.f, 0.f, 0.f, 0.f};
#pragma unroll
    for (int i = 0; i < 4; ++i)
#pragma unroll
        for (int j = 0; j < 4; ++j) acc[i][j] = z4;

    if (bid >= SU_GI0) {
        const int ti = bid - SU_GI0;
        const int t = ti / 12, nt = ti - t * 12;
        const int n0 = nt * 128;
        const int ar0 = captions[s_ord[srow]      * L_ + t];
        const int ar1 = captions[s_ord[srow + 64] * L_ + t];
        const int br0 = n0 + srow, br1 = n0 + srow + 64;
        const float* Wt = W_ih + IC_;

        uint4 a0 = load_cvt<true>(embed_w, (size_t)ar0 * WD_ + ch * 8);
        uint4 a1 = load_cvt<true>(embed_w, (size_t)ar1 * WD_ + ch * 8);
        uint4 b0 = load_cvt<true>(Wt, (size_t)br0 * D_ + ch * 8);
        uint4 b1 = load_cvt<true>(Wt, (size_t)br1 * D_ + ch * 8);

        for (int k0 = 0; k0 < WD_; k0 += 32) {
            __syncthreads();
            *(uint4*)&As[(srow)      * 32 + ch * 8] = a0;
            *(uint4*)&As[(srow + 64) * 32 + ch * 8] = a1;
            *(uint4*)&Bs[(srow)      * 32 + ch * 8] = b0;
            *(uint4*)&Bs[(srow + 64) * 32 + ch * 8] = b1;
            __syncthreads();
            short8 af[4], bfr[4];
#pragma unroll
            for (int i = 0; i < 4; ++i) af[i]  = *(const short8*)&As[(wm + i * 16 + lr) * 32 + quad * 8];
#pragma unroll
            for (int j = 0; j < 4; ++j) bfr[j] = *(const short8*)&Bs[(wn + j * 16 + lr) * 32 + quad * 8];
            if (k0 + 32 < WD_) {
                a0 = load_cvt<true>(embed_w, (size_t)ar0 * WD_ + k0 + 32 + ch * 8);
                a1 = load_cvt<true>(embed_w, (size_t)ar1 * WD_ + k0 + 32 + ch * 8);
                b0 = load_cvt<true>(Wt, (size_t)br0 * D_ + k0 + 32 + ch * 8);
                b1 = load_cvt<true>(Wt, (size_t)br1 * D_ + k0 + 32 + ch * 8);
            }
#pragma unroll
            for (int i = 0; i < 4; ++i)
#pragma unroll
                for (int j = 0; j < 4; ++j) acc[i][j] = mfma16(af[i], bfr[j], acc[i][j]);
        }

#pragma unroll
        for (int i = 0; i < 4; ++i)
#pragma unroll
            for (int r = 0; r < 4; ++r) {
                const int m = t * 128 + wm + i * 16 + quad * 4 + r;
#pragma unroll
                for (int j = 0; j < 4; ++j) {
                    const int n = n0 + wn + j * 16 + lr;
                    gi_wemb[(size_t)m * G3_ + n] = f2bf(acc[i][j][r]);
                }
            }
        return;
    }

    // ---- pfx: gi_img (bids 1..12) / h0 (bids 13..16), K = 2048 ----
    const int px = bid - SU_PFX0;
    const bool isH0 = px >= 12;
    const float* Bm = isH0 ? init_w : W_ih;
    const int ldb = isH0 ? IC_ : D_;
    const int n0 = isH0 ? (px - 12) * 128 : px * 128;
    const float* bias = isH0 ? init_b : b_ih;

    const int ar0 = s_ord[srow];
    const int ar1 = s_ord[srow + 64];
    const int br0 = n0 + srow, br1 = n0 + srow + 64;

    uint4 a0 = load_cvt<true>(image_code, (size_t)ar0 * IC_ + ch * 8);
    uint4 a1 = load_cvt<true>(image_code, (size_t)ar1 * IC_ + ch * 8);
    uint4 b0 = load_cvt<true>(Bm, (size_t)br0 * ldb + ch * 8);
    uint4 b1 = load_cvt<true>(Bm, (size_t)br1 * ldb + ch * 8);

    for (int k0 = 0; k0 < IC_; k0 += 32) {
        __syncthreads();
        *(uint4*)&As[(srow)      * 32 + ch * 8] = a0;
        *(uint4*)&As[(srow + 64) * 32 + ch * 8] = a1;
        *(uint4*)&Bs[(srow)      * 32 + ch * 8] = b0;
        *(uint4*)&Bs[(srow + 64) * 32 + ch * 8] = b1;
        __syncthreads();
        short8 af[4], bfr[4];
#pragma unroll
        for (int i = 0; i < 4; ++i) af[i]  = *(const short8*)&As[(wm + i * 16 + lr) * 32 + quad * 8];
#pragma unroll
        for (int j = 0; j < 4; ++j) bfr[j] = *(const short8*)&Bs[(wn + j * 16 + lr) * 32 + quad * 8];
        if (k0 + 32 < IC_) {
            a0 = load_cvt<true>(image_code, (size_t)ar0 * IC_ + k0 + 32 + ch * 8);
            a1 = load_cvt<true>(image_code, (size_t)ar1 * IC_ + k0 + 32 + ch * 8);
            b0 = load_cvt<true>(Bm, (size_t)br0 * ldb + k0 + 32 + ch * 8);
            b1 = load_cvt<true>(Bm, (size_t)br1 * ldb + k0 + 32 + ch * 8);
        }
#pragma unroll
        for (int i = 0; i < 4; ++i)
#pragma unroll
            for (int j = 0; j < 4; ++j) acc[i][j] = mfma16(af[i], bfr[j], acc[i][j]);
    }

#pragma unroll
    for (int i = 0; i < 4; ++i)
#pragma unroll
        for (int r = 0; r < 4; ++r) {
            const int m = wm + i * 16 + quad * 4 + r;
#pragma unroll
            for (int j = 0; j < 4; ++j) {
                const int n = n0 + wn + j * 16 + lr;
                const float v = acc[i][j][r] + bias[n];
                if (isH0) outs[(size_t)m * H_ + n] = f2bf(v);
                else      gi_img[(size_t)m * G3_ + n] = v;
            }
        }
}

// ---------------------------------------------------------------------------
// FUSED recurrence + output projection (R12).
// Producer: R7 verbatim. Consumer k-loop: T3/T4 counted-pipeline --
//  * 16 HAND-UNROLLED iters, 3-deep rotation over 12 NAMED uint4 regs
//    (R11's arrays were demoted to LDS: +48KB LDS block = 192B x 256 thr);
//  * raw __builtin_amdgcn_s_barrier() + explicit lgkmcnt(0) instead of
//    __syncthreads: NO vmcnt(0) drain at barriers, so prefetch loads issued
//    3 iters (~600-900cy) ahead stay in flight across barriers; compiler's
//    per-register vmcnt waits handle consumption.
//  Safety: removed drain protected only prefetch loads (consumed via reg
//  dependence) and out-stores (unread in-kernel); LDS ordering preserved by
//  lgkmcnt(0) on both sides of each barrier; barrier counts uniform.
// ---------------------------------------------------------------------------
#define PBS_STR 520

#define LOAD_CHUNK(C, K) \
    C##a0 = *(const uint4*)&A[(size_t)srow * 512 + (K) + ch * 8]; \
    C##a1 = *(const uint4*)&A[(size_t)(srow + 64) * 512 + (K) + ch * 8]; \
    C##b0 = *(const uint4*)&fcw_bf[(size_t)(n0 + srow) * 512 + (K) + ch * 8]; \
    C##b1 = *(const uint4*)&fcw_bf[(size_t)(n0 + srow + 64) * 512 + (K) + ch * 8];

#define K_ITER(C, KNEXT, DOLOAD) \
    asm volatile("s_waitcnt lgkmcnt(0)" ::: "memory"); \
    __builtin_amdgcn_s_barrier(); \
    *(uint4*)&As[(srow)      * 32 + ch * 8] = C##a0; \
    *(uint4*)&As[(srow + 64) * 32 + ch * 8] = C##a1; \
    *(uint4*)&Bs[(srow)      * 32 + ch * 8] = C##b0; \
    *(uint4*)&Bs[(srow + 64) * 32 + ch * 8] = C##b1; \
    asm volatile("s_waitcnt lgkmcnt(0)" ::: "memory"); \
    __builtin_amdgcn_s_barrier(); \
    { \
        short8 af[4], bfr[4]; \
        _Pragma("unroll") \
        for (int i = 0; i < 4; ++i) af[i]  = *(const short8*)&As[(wm + i * 16 + lr) * 32 + quad * 8]; \
        _Pragma("unroll") \
        for (int j = 0; j < 4; ++j) bfr[j] = *(const short8*)&Bs[(wn + j * 16 + lr) * 32 + quad * 8]; \
        if (DOLOAD) { LOAD_CHUNK(C, KNEXT) } \
        _Pragma("unroll") \
        for (int i = 0; i < 4; ++i) \
            _Pragma("unroll") \
            for (int j = 0; j < 4; ++j) acc[i][j] = mfma16(af[i], bfr[j], acc[i][j]); \
    }

__global__ __launch_bounds__(256, 1) void k_fused(
    const ushort_t* __restrict__ whh_bf,   // (32,48,512)
    const ushort_t* __restrict__ gi_wemb,  // (31*128,1536) pure emb part
    const float* __restrict__ b_hh,        // (1536)
    ushort_t* __restrict__ outs,           // (32,128,512)
    const ushort_t* __restrict__ fcw_bf,   // (10112,512)
    const float* __restrict__ fc_b,        // (10000)
    const int* __restrict__ len_i,         // (128)
    float* __restrict__ out,               // (128,31,10000)
    int* __restrict__ sync,                // distributed flags (fcw pad rows)
    const float* __restrict__ gi_img)      // (128,1536) f32
{
    __shared__ __align__(16) ushort_t sm[43008];   // 86,016 B -> 1 block/CU
    const int bid = blockIdx.x;
    const int tid = threadIdx.x;
    const int w = tid >> 6, lane = tid & 63, quad = lane >> 4, lr = lane & 15;

    if (bid < NPROD_) {
        // ---------------- producer (solo CU) -- R7 verbatim ----------------
        __builtin_amdgcn_s_setprio(1);
        const int g = bid & 31;
        const int ih = bid >> 5;
        const bool leader = (bid == (ih << 5));   // bid 0 and 32
        ushort_t* Bs = sm;                 // 48 x 520

        const ushort_t* wsrc = whh_bf + (size_t)g * 48 * 512;
        for (int i = tid; i < 48 * 64; i += 256) {
            const int row = i >> 6, c = i & 63;
            *(uint4*)&Bs[row * PBS_STR + c * 8] = *(const uint4*)&wsrc[row * 512 + c * 8];
        }
        const int cg = g * 16 + lr;        // gh col
        const float bhr = b_hh[cg];
        const float bhz = b_hh[512 + cg];
        const float bhn = b_hh[1024 + cg];
        __syncthreads();

        float gim0[4], gim1[4], gim2[4];
        float hold_reg[4];
        {
            const ushort_t* h0p = outs + (size_t)ih * 64 * 512;
#pragma unroll
            for (int r = 0; r < 4; ++r) {
                const int b = ih * 64 + w * 16 + quad * 4 + r;
                const float* pim = gi_img + (size_t)b * G3_ + cg;
                gim0[r] = pim[0]; gim1[r] = pim[512]; gim2[r] = pim[1024];
                hold_reg[r] = bf2f(h0p[(size_t)(w * 16 + quad * 4 + r) * 512 + cg]);
            }
        }
        ushort_t gi0[4], gi1[4], gi2[4];
#pragma unroll
        for (int r = 0; r < 4; ++r) {
            const int b = ih * 64 + w * 16 + quad * 4 + r;
            const ushort_t* p = gi_wemb + (size_t)b * G3_ + cg;
            gi0[r] = p[0]; gi1[r] = p[512]; gi2[r] = p[1024];
        }

        for (int step = 0; step < T_; ++step) {
            const ushort_t* hsrc = outs + (size_t)step * (128 * 512) + (size_t)ih * 64 * 512;

            uint4 hv[16];
            const ushort_t* hrow = hsrc + (size_t)(w * 16 + lr) * 512 + quad * 8;
#pragma unroll
            for (int kk = 0; kk < 16; ++kk)
                hv[kk] = *(const uint4*)(hrow + kk * 32);

            f32x4 acc[3];
#pragma unroll
            for (int j = 0; j < 3; ++j) acc[j] = (f32x4){0.f, 0.f, 0.f, 0.f};
#pragma unroll
            for (int kk = 0; kk < 16; ++kk) {
                union { uint4 v; short8 s; } cc; cc.v = hv[kk];
                const short8 af = cc.s;
#pragma unroll
                for (int j = 0; j < 3; ++j) {
                    const short8 bf = *(const short8*)&Bs[(j * 16 + lr) * PBS_STR + kk * 32 + quad * 8];
                    acc[j] = mfma16(af, bf, acc[j]);
                }
            }

            ushort_t* hdst = outs + (size_t)(step + 1) * (128 * 512);
#pragma unroll
            for (int r = 0; r < 4; ++r) {
                const int b = ih * 64 + w * 16 + quad * 4 + r;
                const float ir  = bf2f(gi0[r]) + gim0[r] + bhr;
                const float iz  = bf2f(gi1[r]) + gim1[r] + bhz;
                const float in_ = bf2f(gi2[r]) + gim2[r];
                const float hr = acc[0][r];
                const float hz = acc[1][r];
                const float hn = acc[2][r] + bhn;
                const float rg = 1.f / (1.f + __expf(-(ir + hr)));
                const float zg = 1.f / (1.f + __expf(-(iz + hz)));
                const float nn = tanhf(in_ + rg * hn);
                const float hnew = (1.f - zg) * nn + zg * hold_reg[r];
                const unsigned int hb = (unsigned int)f2bf(hnew);
                hold_reg[r] = bf2f((unsigned short)hb);   // bit-compat carry
                const unsigned int pv = (unsigned int)__shfl_xor((int)hb, 1);
                if ((lr & 1) == 0) {
                    const unsigned int word = hb | (pv << 16);
                    __hip_atomic_store((unsigned int*)&hdst[(size_t)b * 512 + cg], word,
                                       __ATOMIC_RELAXED, __HIP_MEMORY_SCOPE_AGENT);
                }
            }

            asm volatile("s_waitcnt vmcnt(0)" ::: "memory");
            __syncthreads();
            const int tgt = step + 1;
            if (tid == 0)
                __hip_atomic_store(&sync[bid * 8], tgt,
                                   __ATOMIC_RELAXED, __HIP_MEMORY_SCOPE_AGENT);

            ushort_t ng0[4], ng1[4], ng2[4];
            if (step + 1 < T_) {
                const size_t gb = (size_t)(step + 1) * 128 * G3_;
#pragma unroll
                for (int r = 0; r < 4; ++r) {
                    const int b = ih * 64 + w * 16 + quad * 4 + r;
                    const ushort_t* p = gi_wemb + gb + (size_t)b * G3_ + cg;
                    ng0[r] = p[0]; ng1[r] = p[512]; ng2[r] = p[1024];
                }
            }
            asm volatile("" ::: "memory");

            if (w == 0 && (step < T_ - 1 || leader)) {
                const int* pf = &sync[(ih * 32 + (lane & 31)) * 8];
                for (;;) {
                    const int v = __hip_atomic_load(pf, __ATOMIC_RELAXED, __HIP_MEMORY_SCOPE_AGENT);
                    if (__all(v >= tgt)) break;
                    __builtin_amdgcn_s_sleep(1);
                }
                if (leader && lane == 0) {
#pragma unroll
                    for (int k = 0; k < 8; ++k)
                        __hip_atomic_store(&sync[768 + k * 16 + ih], tgt,
                                           __ATOMIC_RELAXED, __HIP_MEMORY_SCOPE_AGENT);
                }
            }
            __syncthreads();          // release waves 1-3
            asm volatile("" ::: "memory");

            if (step + 1 < T_) {
#pragma unroll
                for (int r = 0; r < 4; ++r) { gi0[r] = ng0[r]; gi1[r] = ng1[r]; gi2[r] = ng2[r]; }
            }
        }
    } else {
        // ---- nb-affine consumer (solo CU) -- counted pipeline (R12) ----
        const int cid = bid - NPROD_;          // [0, 158)
        const int nb = cid % 79;               // FIXED fcw slab per block
        const int team = cid / 79;             // {0, 1}
        const int n0 = nb * 128;
        ushort_t* As = sm;            // 128 x 32
        ushort_t* Bs = sm + 4096;     // 128 x 32
        const int srow = tid >> 2, ch = tid & 3;
        const int wm = (w & 1) * 64, wn = (w >> 1) * 64;
        const ull_t* hready = (const ull_t*)&sync[768 + (cid & 7) * 16];

        float fcb[4];
#pragma unroll
        for (int j = 0; j < 4; ++j) {
            const int n = n0 + wn + j * 16 + lr;
            fcb[j] = (n < V_) ? fc_b[n] : 0.f;
        }

        for (int t = team; t < T_; t += NTEAM_) {
            if (tid == 0) {
                for (;;) {
                    const ull_t hv8 = __hip_atomic_load(hready, __ATOMIC_RELAXED, __HIP_MEMORY_SCOPE_AGENT);
                    const int l0 = (int)(unsigned int)(hv8 & 0xffffffffull);
                    const int l1 = (int)(unsigned int)(hv8 >> 32);
                    if (l0 > t && l1 > t) break;
                    __builtin_amdgcn_s_sleep(16);
                }
            }
            __syncthreads();   // tile boundary (drains prior out-stores too)

            const ushort_t* A = outs + (size_t)(t + 1) * (128 * 512);

            f32x4 acc[4][4];
            const f32x4 z4 = {0.f, 0.f, 0.f, 0.f};
#pragma unroll
            for (int i = 0; i < 4; ++i)
#pragma unroll
                for (int j = 0; j < 4; ++j) acc[i][j] = z4;

            // 12 NAMED registers (no arrays -> no LDS demotion)
            uint4 cAa0, cAa1, cAb0, cAb1;
            uint4 cBa0, cBa1, cBb0, cBb1;
            uint4 cCa0, cCa1, cCb0, cCb1;
            LOAD_CHUNK(cA, 0)
            LOAD_CHUNK(cB, 32)
            LOAD_CHUNK(cC, 64)

            K_ITER(cA,  96, true)   // it 0  (loads chunk 3)
            K_ITER(cB, 128, true)   // it 1
            K_ITER(cC, 160, true)   // it 2
            K_ITER(cA, 192, true)   // it 3
            K_ITER(cB, 224, true)   // it 4
            K_ITER(cC, 256, true)   // it 5
            K_ITER(cA, 288, true)   // it 6
            K_ITER(cB, 320, true)   // it 7
            K_ITER(cC, 352, true)   // it 8
            K_ITER(cA, 384, true)   // it 9
            K_ITER(cB, 416, true)   // it 10
            K_ITER(cC, 448, true)   // it 11
            K_ITER(cA, 480, true)   // it 12 (loads chunk 15)
            K_ITER(cB, 0, false)    // it 13
            K_ITER(cC, 0, false)    // it 14
            K_ITER(cA, 0, false)    // it 15

#pragma unroll
            for (int i = 0; i < 4; ++i)
#pragma unroll
                for (int r = 0; r < 4; ++r) {
                    const int b = wm + i * 16 + quad * 4 + r;
                    const bool act = (t < len_i[b]);
                    const size_t base = (size_t)b * T_ * V_ + (size_t)t * V_;
#pragma unroll
                    for (int j = 0; j < 4; ++j) {
                        const int n = n0 + wn + j * 16 + lr;
                        if (n < V_) out[base + n] = act ? (acc[i][j][r] + fcb[j]) : 0.f;
                    }
                }
        }
    }
}

// ---------------------------------------------------------------------------
extern "C" void kernel_launch(void* const* d_in, const int* in_sizes, int n_in,
                              void* d_out, int out_size, void* d_ws, size_t ws_size,
                              hipStream_t stream) {
    const float* image_code = (const float*)d_in[0];
    const int*   captions   = (const int*)d_in[1];
    const int*   cap_lens   = (const int*)d_in[2];
    const float* embed_w    = (const float*)d_in[3];
    const float* W_ih       = (const float*)d_in[4];
    const float* W_hh       = (const float*)d_in[5];
    const float* b_ih       = (const float*)d_in[6];
    const float* b_hh       = (const float*)d_in[7];
    const float* fc_w       = (const float*)d_in[8];
    const float* fc_b       = (const float*)d_in[9];
    const float* init_w     = (const float*)d_in[10];
    const float* init_b     = (const float*)d_in[11];

    float* out = (float*)d_out;
    char* ws = (char*)d_ws;
    int*      order   = (int*)(ws + WS_ORDER);
    int*      len_i   = (int*)(ws + WS_LEN);
    int*      bar     = (int*)(ws + WS_BAR);
    float*    gi_img  = (float*)(ws + WS_GIIMG);
    ushort_t* whh_bf  = (ushort_t*)(ws + WS_WHH);
    ushort_t* gi_wemb = (ushort_t*)(ws + WS_GIWEMB);
    ushort_t* outs_bf = (ushort_t*)(ws + WS_OUTS);
    ushort_t* fcw_bf  = (ushort_t*)(ws + WS_FCW);
    int*      sync    = (int*)(fcw_bf + ((size_t)NPAD_ - 4) * 512);

    // 1) one setup launch: prep + pfx + gi_wemb gemm + both weight converts
    hipLaunchKernelGGL(k_setup, dim3(SU_N), dim3(256), 0, stream,
                       captions, cap_lens, fc_w, W_hh,
                       image_code, W_ih, b_ih, init_w, init_b, embed_w,
                       fcw_bf, whh_bf, gi_img, gi_wemb, outs_bf,
                       order, len_i, bar,
                       out + (size_t)B_ * T_ * V_);

    // 2) fused persistent recurrence + streaming output projection
    hipLaunchKernelGGL(k_fused, dim3(NPROD_ + NCONS_), dim3(256), 0, stream,
                       whh_bf, gi_wemb, b_hh, outs_bf,
                       fcw_bf, fc_b, len_i, out, sync, gi_img);
}